// Round 8
// baseline (714.364 us; speedup 1.0000x reference)
//
#include <hip/hip_runtime.h>

// 2-layer LSTM (H=64, D=1), N=2048, T=512 — MFMA bf16 3-term split precision.
// R8 = R7 with the output-flush schedule fixed (R7's only correctness bug:
// first flush guard could never fire -> j=1..62 never written; j=447 fell
// between in-loop flushes and the tail flush).
// 4-role pipeline, 16 waves (4/SIMD), 128 blocks x 1024 threads.
//  E (w0-3):  L1 MFMA (24) + gates rows 0-1        [Whh1 hi+lo = 64 regs]
//  G (w4-7):  L1 gates rows 2-3 + out-dot + flush  [no weight regs]
//  O (w8-11): L2 Wih2-half MFMA (24) + gates r0-1  [64 regs]
//  P (w12-15):L2 Whh2-half MFMA (24) + gates r2-3  [64 regs]
// Pre-activation halves exchanged via LDS at the mid-barrier (8 fl/lane).
// 2 barriers/step; outputs staged in a 128-slot ring, flushed every 64 steps.

typedef __attribute__((ext_vector_type(8))) short short8;
typedef __attribute__((ext_vector_type(4))) float f32x4;
typedef __attribute__((ext_vector_type(4))) unsigned short u16x4;

#define NT 512
#define XPITCH 2060              // 515 words (odd) -> conflict-free x reads
#define XP   0                   // 16 * 2060 = 32960
#define HP   32960               // 8 planes * 2304 = 18432
#define ACCE 51392               // 4 * 2048: E -> G  (L1 acc rows 2-3)
#define ACCO 59584               // 4 * 2048: O -> P  (L2 partial rows 2-3, incl bias)
#define ACCP 67776               // 4 * 2048: P -> O  (L2 partial rows 0-1)
#define RING 75968               // 128 slots * 16 samples * 4B
#define B1L  84160               // 256 f32: bih1+bhh1 by row
#define W1L  85184               // 256 f32: Wih1 by row
#define B2L  86208               // 256 f32: bih2+bhh2 by row
#define LDS_BYTES 87232
#define PLANE(layer, buf, hl) (HP + ((((layer) * 2 + (buf)) * 2) + (hl)) * 2304)

__device__ __forceinline__ float fast_rcp(float x) { return __builtin_amdgcn_rcpf(x); }
__device__ __forceinline__ unsigned short bf_rne(float f) {
  unsigned u = __float_as_uint(f);
  return (unsigned short)((u + 0x7FFFu + ((u >> 16) & 1u)) >> 16);
}
__device__ __forceinline__ void split8(const float* p, short8& hi, short8& lo) {
#pragma unroll
  for (int e = 0; e < 8; ++e) {
    float v = p[e];
    unsigned short h = bf_rne(v);
    float hf = __uint_as_float(((unsigned)h) << 16);
    hi[e] = (short)h;
    lo[e] = (short)bf_rne(v - hf);
  }
}
__device__ __forceinline__ unsigned cvt_pk(float a, float b) {
  unsigned r;
  asm("v_cvt_pk_bf16_f32 %0, %1, %2" : "=v"(r) : "v"(a), "v"(b));
  return r;
}
__device__ __forceinline__ f32x4 mfma16(short8 a, short8 b, f32x4 c) {
  return __builtin_amdgcn_mfma_f32_16x16x32_bf16(a, b, c, 0, 0, 0);
}
// (c,h) update from 4 gate pre-activations. Combined-rcp form, 5 exp + 3 rcp.
__device__ __forceinline__ void cell(float i, float f, float gg, float o,
                                     float& c, float& h) {
  const float ei = __expf(-i), ef = __expf(-f), eg = __expf(-2.f * gg),
              eo = __expf(-o);
  const float P = (1.f - eg) * fast_rcp((1.f + ei) * (1.f + eg));
  c = fmaf(c, fast_rcp(1.f + ef), P);
  const float cc = fminf(15.f, fmaxf(-15.f, c));
  const float ec = __expf(-2.f * cc);
  h = (1.f - ec) * fast_rcp((1.f + eo) * (1.f + ec));
}
__device__ __forceinline__ void flush_block(const char* smem, float* out,
                                            int s0, int f0, int thr) {
  const int s2 = thr >> 4, iq = thr & 15;
  float* ob = out + (size_t)(s0 + s2) * 511;
#pragma unroll
  for (int u = 0; u < 4; ++u) {
    const int j = f0 + iq * 4 + u;
    if (j >= 1 && j <= 511)
      ob[j - 1] = *(const float*)(smem + RING + (j & 127) * 64 + s2 * 4);
  }
}

__global__ __launch_bounds__(1024, 4) void lstm2_pipe4(
    const float* __restrict__ y, const float* __restrict__ Wih1,
    const float* __restrict__ Whh1, const float* __restrict__ bih1,
    const float* __restrict__ bhh1, const float* __restrict__ Wih2,
    const float* __restrict__ Whh2, const float* __restrict__ bih2,
    const float* __restrict__ bhh2, const float* __restrict__ Wlin,
    const float* __restrict__ blin, float* __restrict__ out) {
  extern __shared__ char smem[];
  const int tid = threadIdx.x;
  const int w = tid >> 6;
  const int wt = w >> 2;           // 0=E 1=G 2=O 3=P
  const int ew = w & 3;            // role-local wave index
  const int lane = tid & 63;
  const int g = lane >> 4;
  const int s = lane & 15;
  const int s0 = blockIdx.x * 16;

  // ---- stage x ----
  for (int i = tid; i < 16 * 512; i += 1024) {
    const int ss = i >> 9, t = i & 511;
    *(float*)(smem + XP + ss * XPITCH + t * 4) = y[(size_t)(s0 + ss) * 512 + t];
  }
  // ---- zero h planes ----
  for (int i = tid; i < 18432 / 4; i += 1024) *(float*)(smem + HP + i * 4) = 0.f;
  // ---- biases / Wih1 to LDS (linear by row) ----
  if (tid < 256) {
    *(float*)(smem + B1L + tid * 4) = bih1[tid] + bhh1[tid];
    *(float*)(smem + W1L + tid * 4) = Wih1[tid];
    *(float*)(smem + B2L + tid * 4) = bih2[tid] + bhh2[tid];
  }

  const int bo0 = s * 144 + 16 * g, bo1 = bo0 + 64;
  const int hwr0 = s * 144 + 32 * ew + 8 * g;

  if (wt == 0) {  // ================= E: L1 MFMA + gates r0-1 =================
    short8 a1h[4][2], a1l[4][2];
#pragma unroll
    for (int p = 0; p < 4; ++p)
#pragma unroll
      for (int c = 0; c < 2; ++c)
        split8(Whh1 + (size_t)(p * 64 + 16 * ew + s) * 64 + 32 * c + 8 * g,
               a1h[p][c], a1l[p][c]);
    float c1[2] = {0.f, 0.f};
    const char* biasp = smem + B1L + (16 * ew + 4 * g) * 4;
    const char* wihp  = smem + W1L + (16 * ew + 4 * g) * 4;
    char* accw = smem + ACCE + ew * 2048 + lane * 32;
    __syncthreads();
#pragma unroll 1
    for (int k = 0; k <= NT; ++k) {
      f32x4 acc[4];
      if (k < NT) {
        const float x = *(const float*)(smem + XP + s * XPITCH + k * 4);
        const int rp0 = PLANE(0, (k - 1) & 1, 0), rp1 = PLANE(0, (k - 1) & 1, 1);
        const short8 Bh0 = *(const short8*)(smem + rp0 + bo0);
        const short8 Bl0 = *(const short8*)(smem + rp1 + bo0);
        const short8 Bh1 = *(const short8*)(smem + rp0 + bo1);
        const short8 Bl1 = *(const short8*)(smem + rp1 + bo1);
#pragma unroll
        for (int p = 0; p < 4; ++p) {
          const f32x4 b4 = *(const f32x4*)(biasp + p * 256);
          const f32x4 w4 = *(const f32x4*)(wihp + p * 256);
          acc[p] = b4 + w4 * x;
        }
        __builtin_amdgcn_s_setprio(1);
#pragma unroll
        for (int p = 0; p < 4; ++p) acc[p] = mfma16(a1h[p][0], Bh0, acc[p]);
#pragma unroll
        for (int p = 0; p < 4; ++p) acc[p] = mfma16(a1h[p][0], Bl0, acc[p]);
#pragma unroll
        for (int p = 0; p < 4; ++p) acc[p] = mfma16(a1l[p][0], Bh0, acc[p]);
#pragma unroll
        for (int p = 0; p < 4; ++p) acc[p] = mfma16(a1h[p][1], Bh1, acc[p]);
#pragma unroll
        for (int p = 0; p < 4; ++p) acc[p] = mfma16(a1h[p][1], Bl1, acc[p]);
#pragma unroll
        for (int p = 0; p < 4; ++p) acc[p] = mfma16(a1l[p][1], Bh1, acc[p]);
        __builtin_amdgcn_s_setprio(0);
        f32x4 A2 = {acc[0][2], acc[1][2], acc[2][2], acc[3][2]};
        f32x4 A3 = {acc[0][3], acc[1][3], acc[2][3], acc[3][3]};
        *(f32x4*)(accw) = A2;
        *(f32x4*)(accw + 16) = A3;
      }
      __syncthreads();
      if (k < NT) {
        float h0, h1;
        cell(acc[0][0], acc[1][0], acc[2][0], acc[3][0], c1[0], h0);
        cell(acc[0][1], acc[1][1], acc[2][1], acc[3][1], c1[1], h1);
        const unsigned hw = cvt_pk(h0, h1);
        const unsigned lw = cvt_pk(h0 - __uint_as_float(hw << 16),
                                   h1 - __uint_as_float(hw & 0xFFFF0000u));
        *(unsigned*)(smem + PLANE(0, k & 1, 0) + hwr0) = hw;
        *(unsigned*)(smem + PLANE(0, k & 1, 1) + hwr0) = lw;
      }
      __syncthreads();
    }
  } else if (wt == 1) {  // ========== G: L1 gates r2-3 + out-dot + flush ======
    const int sL = ew * 4 + (lane >> 4);
    const int q = lane & 15;
    float wl4[4];
#pragma unroll
    for (int r = 0; r < 4; ++r) wl4[r] = Wlin[4 * q + r];
    const float bl0 = blin[0];
    float c1g[2] = {0.f, 0.f};
    const char* accr = smem + ACCE + ew * 2048 + lane * 32;
    const int doff = sL * 144 + q * 8;
    __syncthreads();
#pragma unroll 1
    for (int k = 0; k <= NT; ++k) {
      if (k >= 3) {  // out value for j = k-2 from h2(k-2) planes (buf k&1)
        const u16x4 h4 = *(const u16x4*)(smem + PLANE(1, k & 1, 0) + doff);
        const u16x4 l4 = *(const u16x4*)(smem + PLANE(1, k & 1, 1) + doff);
        float pw = 0.f;
#pragma unroll
        for (int r = 0; r < 4; ++r) {
          const float hv = __uint_as_float(((unsigned)h4[r]) << 16) +
                           __uint_as_float(((unsigned)l4[r]) << 16);
          pw = fmaf(wl4[r], hv, pw);
        }
        pw += __shfl_xor(pw, 1, 64);
        pw += __shfl_xor(pw, 2, 64);
        pw += __shfl_xor(pw, 4, 64);
        pw += __shfl_xor(pw, 8, 64);
        if (q == 0)
          *(float*)(smem + RING + ((k - 2) & 127) * 64 + sL * 4) = pw + bl0;
      }
      // FIX(R8): fire at k=65,129,...,449 -> covers j=1..446 (R7's `k>=66`
      // skipped the k=65 flush entirely, losing j=1..62).
      if (k >= 65 && (k & 63) == 1) flush_block(smem, out, s0, k - 66, ew * 64 + lane);
      __syncthreads();
      if (k < NT) {
        const f32x4 A2 = *(const f32x4*)(accr);
        const f32x4 A3 = *(const f32x4*)(accr + 16);
        float h0, h1;
        cell(A2[0], A2[1], A2[2], A2[3], c1g[0], h0);
        cell(A3[0], A3[1], A3[2], A3[3], c1g[1], h1);
        const unsigned hw = cvt_pk(h0, h1);
        const unsigned lw = cvt_pk(h0 - __uint_as_float(hw << 16),
                                   h1 - __uint_as_float(hw & 0xFFFF0000u));
        *(unsigned*)(smem + PLANE(0, k & 1, 0) + hwr0 + 4) = hw;
        *(unsigned*)(smem + PLANE(0, k & 1, 1) + hwr0 + 4) = lw;
      }
      __syncthreads();
    }
  } else if (wt == 2) {  // ========== O: L2 Wih2-half MFMA + gates r0-1 =======
    short8 a2h[4][2], a2l[4][2];
#pragma unroll
    for (int p = 0; p < 4; ++p)
#pragma unroll
      for (int c = 0; c < 2; ++c)
        split8(Wih2 + (size_t)(p * 64 + 16 * ew + s) * 64 + 32 * c + 8 * g,
               a2h[p][c], a2l[p][c]);
    float c2[2] = {0.f, 0.f};
    const char* biasp = smem + B2L + (16 * ew + 4 * g) * 4;
    char* accw = smem + ACCO + ew * 2048 + lane * 32;       // r2-3 partial out
    const char* accr = smem + ACCP + ew * 2048 + lane * 32; // r0-1 partial in
    __syncthreads();
#pragma unroll 1
    for (int k = 0; k <= NT; ++k) {
      f32x4 acc[4];
      if (k >= 1) {
        const int rp0 = PLANE(0, (k - 1) & 1, 0), rp1 = PLANE(0, (k - 1) & 1, 1);
        const short8 Bh0 = *(const short8*)(smem + rp0 + bo0);
        const short8 Bl0 = *(const short8*)(smem + rp1 + bo0);
        const short8 Bh1 = *(const short8*)(smem + rp0 + bo1);
        const short8 Bl1 = *(const short8*)(smem + rp1 + bo1);
#pragma unroll
        for (int p = 0; p < 4; ++p) acc[p] = *(const f32x4*)(biasp + p * 256);
        __builtin_amdgcn_s_setprio(1);
#pragma unroll
        for (int p = 0; p < 4; ++p) acc[p] = mfma16(a2h[p][0], Bh0, acc[p]);
#pragma unroll
        for (int p = 0; p < 4; ++p) acc[p] = mfma16(a2h[p][0], Bl0, acc[p]);
#pragma unroll
        for (int p = 0; p < 4; ++p) acc[p] = mfma16(a2l[p][0], Bh0, acc[p]);
#pragma unroll
        for (int p = 0; p < 4; ++p) acc[p] = mfma16(a2h[p][1], Bh1, acc[p]);
#pragma unroll
        for (int p = 0; p < 4; ++p) acc[p] = mfma16(a2h[p][1], Bl1, acc[p]);
#pragma unroll
        for (int p = 0; p < 4; ++p) acc[p] = mfma16(a2l[p][1], Bh1, acc[p]);
        __builtin_amdgcn_s_setprio(0);
        f32x4 A2 = {acc[0][2], acc[1][2], acc[2][2], acc[3][2]};
        f32x4 A3 = {acc[0][3], acc[1][3], acc[2][3], acc[3][3]};
        *(f32x4*)(accw) = A2;
        *(f32x4*)(accw + 16) = A3;
      }
      __syncthreads();
      if (k >= 1) {
        const f32x4 R0 = *(const f32x4*)(accr);
        const f32x4 R1 = *(const f32x4*)(accr + 16);
        float h0, h1;
        cell(acc[0][0] + R0[0], acc[1][0] + R0[1], acc[2][0] + R0[2],
             acc[3][0] + R0[3], c2[0], h0);
        cell(acc[0][1] + R1[0], acc[1][1] + R1[1], acc[2][1] + R1[2],
             acc[3][1] + R1[3], c2[1], h1);
        const unsigned hw = cvt_pk(h0, h1);
        const unsigned lw = cvt_pk(h0 - __uint_as_float(hw << 16),
                                   h1 - __uint_as_float(hw & 0xFFFF0000u));
        *(unsigned*)(smem + PLANE(1, (k - 1) & 1, 0) + hwr0) = hw;
        *(unsigned*)(smem + PLANE(1, (k - 1) & 1, 1) + hwr0) = lw;
      }
      __syncthreads();
    }
  } else {  // ================= P: L2 Whh2-half MFMA + gates r2-3 ============
    short8 a2h[4][2], a2l[4][2];
#pragma unroll
    for (int p = 0; p < 4; ++p)
#pragma unroll
      for (int c = 0; c < 2; ++c)
        split8(Whh2 + (size_t)(p * 64 + 16 * ew + s) * 64 + 32 * c + 8 * g,
               a2h[p][c], a2l[p][c]);
    float c2[2] = {0.f, 0.f};
    char* accw = smem + ACCP + ew * 2048 + lane * 32;       // r0-1 partial out
    const char* accr = smem + ACCO + ew * 2048 + lane * 32; // r2-3 partial in
    __syncthreads();
#pragma unroll 1
    for (int k = 0; k <= NT; ++k) {
      f32x4 acc[4];
      if (k >= 1) {
        const int rp0 = PLANE(1, k & 1, 0), rp1 = PLANE(1, k & 1, 1); // h2(k-2)
        const short8 Bh0 = *(const short8*)(smem + rp0 + bo0);
        const short8 Bl0 = *(const short8*)(smem + rp1 + bo0);
        const short8 Bh1 = *(const short8*)(smem + rp0 + bo1);
        const short8 Bl1 = *(const short8*)(smem + rp1 + bo1);
#pragma unroll
        for (int p = 0; p < 4; ++p) acc[p] = 0.f;
        __builtin_amdgcn_s_setprio(1);
#pragma unroll
        for (int p = 0; p < 4; ++p) acc[p] = mfma16(a2h[p][0], Bh0, acc[p]);
#pragma unroll
        for (int p = 0; p < 4; ++p) acc[p] = mfma16(a2h[p][0], Bl0, acc[p]);
#pragma unroll
        for (int p = 0; p < 4; ++p) acc[p] = mfma16(a2l[p][0], Bh0, acc[p]);
#pragma unroll
        for (int p = 0; p < 4; ++p) acc[p] = mfma16(a2h[p][1], Bh1, acc[p]);
#pragma unroll
        for (int p = 0; p < 4; ++p) acc[p] = mfma16(a2h[p][1], Bl1, acc[p]);
#pragma unroll
        for (int p = 0; p < 4; ++p) acc[p] = mfma16(a2l[p][1], Bh1, acc[p]);
        __builtin_amdgcn_s_setprio(0);
        f32x4 A0 = {acc[0][0], acc[1][0], acc[2][0], acc[3][0]};
        f32x4 A1 = {acc[0][1], acc[1][1], acc[2][1], acc[3][1]};
        *(f32x4*)(accw) = A0;
        *(f32x4*)(accw + 16) = A1;
      }
      __syncthreads();
      if (k >= 1) {
        const f32x4 R2 = *(const f32x4*)(accr);
        const f32x4 R3 = *(const f32x4*)(accr + 16);
        float h0, h1;
        cell(acc[0][2] + R2[0], acc[1][2] + R2[1], acc[2][2] + R2[2],
             acc[3][2] + R2[3], c2[0], h0);
        cell(acc[0][3] + R3[0], acc[1][3] + R3[1], acc[2][3] + R3[2],
             acc[3][3] + R3[3], c2[1], h1);
        const unsigned hw = cvt_pk(h0, h1);
        const unsigned lw = cvt_pk(h0 - __uint_as_float(hw << 16),
                                   h1 - __uint_as_float(hw & 0xFFFF0000u));
        *(unsigned*)(smem + PLANE(1, (k - 1) & 1, 0) + hwr0 + 4) = hw;
        *(unsigned*)(smem + PLANE(1, (k - 1) & 1, 1) + hwr0 + 4) = lw;
      }
      __syncthreads();
    }
  }

  // ---- tail: out(511) dot + final flush of j = 447..511 ----
  if (wt == 1) {
    const int sL = ew * 4 + (lane >> 4);
    const int q = lane & 15;
    const int doff = sL * 144 + q * 8;
    const u16x4 h4 = *(const u16x4*)(smem + PLANE(1, 1, 0) + doff);
    const u16x4 l4 = *(const u16x4*)(smem + PLANE(1, 1, 1) + doff);
    float pw = 0.f;
#pragma unroll
    for (int r = 0; r < 4; ++r) {
      const float hv = __uint_as_float(((unsigned)h4[r]) << 16) +
                       __uint_as_float(((unsigned)l4[r]) << 16);
      pw = fmaf(Wlin[4 * q + r], hv, pw);
    }
    pw += __shfl_xor(pw, 1, 64);
    pw += __shfl_xor(pw, 2, 64);
    pw += __shfl_xor(pw, 4, 64);
    pw += __shfl_xor(pw, 8, 64);
    if (q == 0)
      *(float*)(smem + RING + (511 & 127) * 64 + sL * 4) = pw + blin[0];
  }
  __syncthreads();
  if (wt == 1) {
    // FIX(R8): in-loop flushes end at j=446; cover j=447..511 (two
    // overlapping 64-wide flushes; overlap rewrites identical values).
    flush_block(smem, out, s0, 447, ew * 64 + lane);
    flush_block(smem, out, s0, 448, ew * 64 + lane);
  }
}

extern "C" void kernel_launch(void* const* d_in, const int* in_sizes, int n_in,
                              void* d_out, int out_size, void* d_ws, size_t ws_size,
                              hipStream_t stream) {
  const float* y    = (const float*)d_in[0];
  const float* Wih1 = (const float*)d_in[1];
  const float* Whh1 = (const float*)d_in[2];
  const float* bih1 = (const float*)d_in[3];
  const float* bhh1 = (const float*)d_in[4];
  const float* Wih2 = (const float*)d_in[5];
  const float* Whh2 = (const float*)d_in[6];
  const float* bih2 = (const float*)d_in[7];
  const float* bhh2 = (const float*)d_in[8];
  const float* Wlin = (const float*)d_in[9];
  const float* blin = (const float*)d_in[10];
  float* out = (float*)d_out;

  hipFuncSetAttribute((const void*)lstm2_pipe4,
                      hipFuncAttributeMaxDynamicSharedMemorySize, LDS_BYTES);
  lstm2_pipe4<<<dim3(128), dim3(1024), LDS_BYTES, stream>>>(
      y, Wih1, Whh1, bih1, bhh1, Wih2, Whh2, bih2, bhh2, Wlin, blin, out);
}